// Round 8
// baseline (275.556 us; speedup 1.0000x reference)
//
#include <hip/hip_runtime.h>

// vanilla_lstm R7 = R6 with the launch-bounds fix. HIP __launch_bounds__ follows
// CUDA semantics: (maxThreadsPerBlock, MIN BLOCKS PER CU) — not waves/EU.
// Session evidence: (512,2)->128 VGPR, (512,4)->64, (1024,4)->64 (clamped).
// (1024,1) -> 16 waves/CU -> 128-VGPR cap = the hard cap for a 1024-thread block.
// 256 blocks x 1024 threads, 1 block/CU. W_hh in LDS as bf16 MFMA B-fragments
// (128 KB) shared by all 16 waves; h double-buffered in LDS (stride 136 -> quad-
// balanced b128 reads); c-state in registers. Decode p>=1 uses the fused
// W_dec = W_hh + W_ih@W_out folded into LDS in place after p=0.

typedef __attribute__((ext_vector_type(8))) short short8;   // 8 x bf16 bits
typedef __attribute__((ext_vector_type(4))) float floatx4;

constexpr int NROW   = 32;                 // rows per block
constexpr int HSTR   = 136;                // h row stride in shorts (16B-aligned, padded)
constexpr int WELEMS = 16 * 128 * 32;      // W fragments: 65536 shorts = 128 KB
constexpr int HELEMS = 2 * NROW * HSTR;    // h double buffer: 8704 shorts
constexpr size_t LDS_BYTES = (size_t)(WELEMS + HELEMS) * sizeof(short);  // 148480

static __device__ __forceinline__ short f2bf(float x) {
  union { float f; unsigned u; } v; v.f = x;
  unsigned r = (v.u + 0x7FFFu + ((v.u >> 16) & 1u)) >> 16;  // RNE
  return (short)r;
}
static __device__ __forceinline__ float bf2f(short b) {
  union { unsigned u; float f; } v; v.u = ((unsigned)(unsigned short)b) << 16;
  return v.f;
}
static __device__ __forceinline__ float sigm(float x) {
  return __builtin_amdgcn_rcpf(1.0f + __expf(-x));
}
static __device__ __forceinline__ float tanh_(float x) {
  return 1.0f - 2.0f * __builtin_amdgcn_rcpf(1.0f + __expf(2.0f * x));
}

__global__ __launch_bounds__(1024, 1) void lstm_fused(
    const float* __restrict__ seq,
    const float* __restrict__ W_ih, const float* __restrict__ W_hh,
    const float* __restrict__ b_ih, const float* __restrict__ b_hh,
    const float* __restrict__ W_out, const float* __restrict__ b_out,
    float* __restrict__ out)
{
  extern __shared__ __align__(16) short lds[];
  short* wlds = lds;             // [(g*4+kk)*128 + c] blocks of 32 bf16 (64 B each)
  short* hbuf = lds + WELEMS;    // [buf][row][col], row stride HSTR

  const int tid = threadIdx.x;
  const int wv  = tid >> 6;      // 0..15
  const int rw  = wv >> 3;       // row-group 0..1  (rows 16rw..16rw+15)
  const int cw  = wv & 7;        // col-group 0..7  (gate-cols 16cw..16cw+15)
  const int L   = tid & 63;
  const int l15 = L & 15;
  const int l4  = L >> 4;        // 0..3
  const int base_row = blockIdx.x * NROW;

  // ---- stage W_hh into LDS as bf16 fragments; zero h buffer 0 ----
  for (int e = tid; e < 16 * 128; e += 1024) {       // e = (g*4+kk)*128 + c
    const int gk = e >> 7;                           // g*4+kk
    const int c  = e & 127;
    const int g  = gk >> 2, kk = gk & 3;
    const float* src = W_hh + (g * 128 + c) * 128 + kk * 32;
    short* dst = wlds + e * 32;
    #pragma unroll
    for (int j = 0; j < 32; ++j) dst[j] = f2bf(src[j]);
  }
  for (int i = tid; i < NROW * HSTR; i += 1024) hbuf[i] = 0;

  float wih[4][4], bias[4], bias_dec[4], c_st[4];
  #pragma unroll
  for (int g = 0; g < 4; ++g) {
    const int col = g * 128 + cw * 16 + l15;
    bias[g] = b_ih[col] + b_hh[col];
    float bd = bias[g];
    #pragma unroll
    for (int f = 0; f < 4; ++f) {
      wih[g][f] = W_ih[col * 4 + f];
      bd = fmaf(b_out[f], wih[g][f], bd);
    }
    bias_dec[g] = bd;
  }
  #pragma unroll
  for (int r = 0; r < 4; ++r) c_st[r] = 0.0f;

  __syncthreads();

  int cur = 0;

  // ===================== encode: t = 0..47 =====================
  for (int t = 0; t < 48; ++t) {
    short8 afr[4];
    #pragma unroll
    for (int kk = 0; kk < 4; ++kk)
      afr[kk] = *(const short8*)&hbuf[cur * NROW * HSTR + (rw * 16 + l15) * HSTR + kk * 32 + l4 * 8];

    floatx4 acc[4];
    #pragma unroll
    for (int g = 0; g < 4; ++g) acc[g] = (floatx4){bias[g], bias[g], bias[g], bias[g]};

    // x-projection in fp32 (K=4) straight into the accumulator
    #pragma unroll
    for (int r = 0; r < 4; ++r) {
      const int row = base_row + rw * 16 + l4 * 4 + r;
      const floatx4 x4 = *(const floatx4*)(seq + row * 192 + t * 4);
      #pragma unroll
      for (int g = 0; g < 4; ++g) {
        float s = acc[g][r];
        #pragma unroll
        for (int f = 0; f < 4; ++f) s = fmaf(x4[f], wih[g][f], s);
        acc[g][r] = s;
      }
    }

    #pragma unroll
    for (int g = 0; g < 4; ++g)
      #pragma unroll
      for (int kk = 0; kk < 4; ++kk) {
        const short8 bfr = *(const short8*)&wlds[((g * 4 + kk) * 128 + cw * 16 + l15) * 32 + l4 * 8];
        acc[g] = __builtin_amdgcn_mfma_f32_16x16x32_bf16(afr[kk], bfr, acc[g], 0, 0, 0);
      }

    #pragma unroll
    for (int r = 0; r < 4; ++r) {
      const float ig = sigm(acc[0][r]);
      const float fg = sigm(acc[1][r]);
      const float gg = tanh_(acc[2][r]);
      const float og = sigm(acc[3][r]);
      const float c  = fg * c_st[r] + ig * gg;
      c_st[r] = c;
      const float h = og * tanh_(c);
      hbuf[(cur ^ 1) * NROW * HSTR + (rw * 16 + l4 * 4 + r) * HSTR + cw * 16 + l15] = f2bf(h);
    }
    __syncthreads();
    cur ^= 1;
  }

  // ---- decode-only constants ----
  short8 wout[4];
  #pragma unroll
  for (int kk = 0; kk < 4; ++kk) {
    short8 fr;
    #pragma unroll
    for (int i = 0; i < 8; ++i)
      fr[i] = (l15 < 4) ? f2bf(W_out[l15 * 128 + kk * 32 + l4 * 8 + i]) : (short)0;
    wout[kk] = fr;
  }
  const float bo = (l15 < 4) ? b_out[l15] : 0.0f;

  // ===================== decode: p = 0..11 =====================
  // p = 0: original W + f32 x-proj of seq[..,47,:]; p >= 1: fused W_dec, no x term.
  for (int p = 0; p < 12; ++p) {
    short8 afr[4];
    #pragma unroll
    for (int kk = 0; kk < 4; ++kk)
      afr[kk] = *(const short8*)&hbuf[cur * NROW * HSTR + (rw * 16 + l15) * HSTR + kk * 32 + l4 * 8];

    floatx4 acc[4];
    if (p == 0) {
      #pragma unroll
      for (int g = 0; g < 4; ++g) acc[g] = (floatx4){bias[g], bias[g], bias[g], bias[g]};
      #pragma unroll
      for (int r = 0; r < 4; ++r) {
        const int row = base_row + rw * 16 + l4 * 4 + r;
        const floatx4 x4 = *(const floatx4*)(seq + row * 192 + 47 * 4);
        #pragma unroll
        for (int g = 0; g < 4; ++g) {
          float s = acc[g][r];
          #pragma unroll
          for (int f = 0; f < 4; ++f) s = fmaf(x4[f], wih[g][f], s);
          acc[g][r] = s;
        }
      }
    } else {
      #pragma unroll
      for (int g = 0; g < 4; ++g)
        acc[g] = (floatx4){bias_dec[g], bias_dec[g], bias_dec[g], bias_dec[g]};
    }

    #pragma unroll
    for (int g = 0; g < 4; ++g)
      #pragma unroll
      for (int kk = 0; kk < 4; ++kk) {
        const short8 bfr = *(const short8*)&wlds[((g * 4 + kk) * 128 + cw * 16 + l15) * 32 + l4 * 8];
        acc[g] = __builtin_amdgcn_mfma_f32_16x16x32_bf16(afr[kk], bfr, acc[g], 0, 0, 0);
      }

    #pragma unroll
    for (int r = 0; r < 4; ++r) {
      const float ig = sigm(acc[0][r]);
      const float fg = sigm(acc[1][r]);
      const float gg = tanh_(acc[2][r]);
      const float og = sigm(acc[3][r]);
      const float c  = fg * c_st[r] + ig * gg;
      c_st[r] = c;
      const float h = og * tanh_(c);
      hbuf[(cur ^ 1) * NROW * HSTR + (rw * 16 + l4 * 4 + r) * HSTR + cw * 16 + l15] = f2bf(h);
    }
    __syncthreads();   // h_p visible in buffer cur^1

    // out_p = h_p @ W_out^T + b_out, by the two waves with cw == (p&7).
    // Safe without trailing barrier: buffer written at p is next overwritten at
    // p+2, gated behind barrier p+1 which these waves join after reading.
    if (cw == (p & 7)) {
      short8 ofr[4];
      #pragma unroll
      for (int kk = 0; kk < 4; ++kk)
        ofr[kk] = *(const short8*)&hbuf[(cur ^ 1) * NROW * HSTR + (rw * 16 + l15) * HSTR + kk * 32 + l4 * 8];
      floatx4 acco = (floatx4){bo, bo, bo, bo};
      #pragma unroll
      for (int kk = 0; kk < 4; ++kk)
        acco = __builtin_amdgcn_mfma_f32_16x16x32_bf16(ofr[kk], wout[kk], acco, 0, 0, 0);
      if (l15 < 4) {
        #pragma unroll
        for (int r = 0; r < 4; ++r)
          out[(base_row + rw * 16 + l4 * 4 + r) * 48 + p * 4 + l15] = acco[r];  // [B,V,P,F]
      }
    }

    // After p=0: fold W_ih @ W_out into the LDS-resident W (W_dec), then barrier
    // so no wave reads W at p=1 before the fold completes. wlds is not read
    // between the step barrier above and this point.
    if (p == 0) {
      for (int e = tid; e < 16 * 128; e += 1024) {
        const int gk = e >> 7;
        const int c  = e & 127;
        const int g  = gk >> 2, kk = gk & 3;
        const int col = g * 128 + c;
        float wi[4];
        #pragma unroll
        for (int f = 0; f < 4; ++f) wi[f] = W_ih[col * 4 + f];
        short* dst = wlds + e * 32;
        #pragma unroll
        for (int j = 0; j < 32; ++j) {
          const int k = kk * 32 + j;
          float v = bf2f(dst[j]);
          #pragma unroll
          for (int f = 0; f < 4; ++f) v = fmaf(wi[f], W_out[f * 128 + k], v);
          dst[j] = f2bf(v);
        }
      }
      __syncthreads();
    }

    cur ^= 1;
  }
}

extern "C" void kernel_launch(void* const* d_in, const int* in_sizes, int n_in,
                              void* d_out, int out_size, void* d_ws, size_t ws_size,
                              hipStream_t stream) {
  const float* seq   = (const float*)d_in[0];
  // d_in[1..5] (dist/bearing/heading matrices, masks) unused by the reference fwd
  const float* W_ih  = (const float*)d_in[6];
  const float* W_hh  = (const float*)d_in[7];
  const float* b_ih  = (const float*)d_in[8];
  const float* b_hh  = (const float*)d_in[9];
  const float* W_out = (const float*)d_in[10];
  const float* b_out = (const float*)d_in[11];

  (void)hipFuncSetAttribute((const void*)lstm_fused,
                            hipFuncAttributeMaxDynamicSharedMemorySize,
                            (int)LDS_BYTES);

  lstm_fused<<<256, 1024, LDS_BYTES, stream>>>(seq, W_ih, W_hh, b_ih, b_hh,
                                               W_out, b_out, (float*)d_out);
}

// Round 9
// 258.530 us; speedup vs baseline: 1.0659x; 1.0659x over previous
//
#include <hip/hip_runtime.h>

// vanilla_lstm R9 = R3 geometry with R2's proven launch bounds.
// Evidence: (512,2) is the ONLY config that compiles to 128 VGPR + zero spill
// (R2: FETCH 4.3MB). 1024-thread blocks pin VGPR=64 + spill regardless of the
// 2nd launch-bounds arg (R6/R8). So: 512 blocks x 16 rows, 512 threads (8 waves),
// 2 blocks/CU -> 4 waves/SIMD. W_hh in VGPRs as bf16 B-frags (64 VGPR); c-state
// in registers; h double-buffered in LDS (stride 136). Decode p>=1 uses fused
// W_dec = W_hh + W_ih@W_out folded into frag1 in place after p=0; wout/bo are
// materialized only in the decode phase to keep the encode live-set ~92 regs.

typedef __attribute__((ext_vector_type(8))) short short8;   // 8 x bf16 bits
typedef __attribute__((ext_vector_type(4))) float floatx4;

static __device__ __forceinline__ short f2bf(float x) {
  union { float f; unsigned u; } v; v.f = x;
  unsigned r = (v.u + 0x7FFFu + ((v.u >> 16) & 1u)) >> 16;  // RNE
  return (short)r;
}
static __device__ __forceinline__ float bf2f(short b) {
  union { unsigned u; float f; } v; v.u = ((unsigned)(unsigned short)b) << 16;
  return v.f;
}
static __device__ __forceinline__ float sigm(float x) {
  return __builtin_amdgcn_rcpf(1.0f + __expf(-x));
}
static __device__ __forceinline__ float tanh_(float x) {
  return 1.0f - 2.0f * __builtin_amdgcn_rcpf(1.0f + __expf(2.0f * x));
}

__global__ __launch_bounds__(512, 2) void lstm_fused(
    const float* __restrict__ seq,
    const float* __restrict__ W_ih, const float* __restrict__ W_hh,
    const float* __restrict__ b_ih, const float* __restrict__ b_hh,
    const float* __restrict__ W_out, const float* __restrict__ b_out,
    float* __restrict__ out)
{
  __shared__ __align__(16) short h_lds[2][16][136];  // bf16 bits, stride 136 (pad)
  __shared__ __align__(16) float wout_f32[4][128];   // W_out staged f32 (for fold)

  const int tid = threadIdx.x;
  const int w   = tid >> 6;      // wave 0..7 -> gate-col group 16w..16w+15
  const int L   = tid & 63;
  const int l15 = L & 15;
  const int l4  = L >> 4;        // 0..3
  const int base_row = blockIdx.x << 4;

  short8 frag1[4][4];   // W_hh B-frags [gate g][k-chunk kk]; col = 128g+16w+l15
  float  wih[4][4];     // W_ih[col][f] fp32
  float  bias[4];       // b_ih+b_hh at lane's col
  float  bias_dec[4];   // bias + (b_out @ W_ih^T) (fused decode)
  float  c_st[4];       // cell state rows 4*l4+r, j = 16w+l15

  // ---- init: zero h buffer 0; stage W_out f32 for the decode fold ----
  {
    short* hp = &h_lds[0][0][0];
    for (int i = tid; i < 16 * 136; i += 512) hp[i] = 0;
    wout_f32[tid >> 7][tid & 127] = W_out[tid];   // 512 threads = 4*128 exactly
  }

  #pragma unroll
  for (int g = 0; g < 4; ++g) {
    const int col = g * 128 + w * 16 + l15;
    bias[g] = b_ih[col] + b_hh[col];
    float bd = bias[g];
    #pragma unroll
    for (int f = 0; f < 4; ++f) {
      wih[g][f] = W_ih[col * 4 + f];
      bd = fmaf(b_out[f], wih[g][f], bd);
    }
    bias_dec[g] = bd;
    #pragma unroll
    for (int kk = 0; kk < 4; ++kk) {
      const float* src = W_hh + col * 128 + kk * 32 + l4 * 8;
      short8 fr;
      #pragma unroll
      for (int i = 0; i < 8; ++i) fr[i] = f2bf(src[i]);
      frag1[g][kk] = fr;
    }
  }
  #pragma unroll
  for (int r = 0; r < 4; ++r) c_st[r] = 0.0f;

  __syncthreads();

  int cur = 0;

  // ===================== encode: t = 0..47 =====================
  for (int t = 0; t < 48; ++t) {
    short8 afr[4];
    #pragma unroll
    for (int kk = 0; kk < 4; ++kk)
      afr[kk] = *(const short8*)&h_lds[cur][l15][kk * 32 + l4 * 8];

    floatx4 acc[4];
    #pragma unroll
    for (int g = 0; g < 4; ++g) acc[g] = (floatx4){bias[g], bias[g], bias[g], bias[g]};

    // x-projection in fp32 (K=4) straight into the accumulator
    #pragma unroll
    for (int r = 0; r < 4; ++r) {
      const int row = base_row + l4 * 4 + r;
      const floatx4 x4 = *(const floatx4*)(seq + row * 192 + t * 4);
      #pragma unroll
      for (int g = 0; g < 4; ++g) {
        float s = acc[g][r];
        #pragma unroll
        for (int f = 0; f < 4; ++f) s = fmaf(x4[f], wih[g][f], s);
        acc[g][r] = s;
      }
    }

    #pragma unroll
    for (int g = 0; g < 4; ++g)
      #pragma unroll
      for (int kk = 0; kk < 4; ++kk)
        acc[g] = __builtin_amdgcn_mfma_f32_16x16x32_bf16(afr[kk], frag1[g][kk], acc[g], 0, 0, 0);

    #pragma unroll
    for (int r = 0; r < 4; ++r) {
      const float ig = sigm(acc[0][r]);
      const float fg = sigm(acc[1][r]);
      const float gg = tanh_(acc[2][r]);
      const float og = sigm(acc[3][r]);
      const float c  = fg * c_st[r] + ig * gg;
      c_st[r] = c;
      const float h = og * tanh_(c);
      h_lds[cur ^ 1][l4 * 4 + r][w * 16 + l15] = f2bf(h);
    }
    __syncthreads();
    cur ^= 1;
  }

  // ---- decode-only constants (kept out of the encode live-range) ----
  short8 wout[4];
  #pragma unroll
  for (int kk = 0; kk < 4; ++kk) {
    short8 fr;
    #pragma unroll
    for (int i = 0; i < 8; ++i)
      fr[i] = (l15 < 4) ? f2bf(wout_f32[l15 & 3][kk * 32 + l4 * 8 + i]) : (short)0;
    wout[kk] = fr;
  }
  const float bo = (l15 < 4) ? b_out[l15] : 0.0f;

  // ===================== decode: p = 0..11 =====================
  // p = 0: original W + f32 x-proj of seq[..,47,:]; p >= 1: fused W_dec, no x term.
  for (int p = 0; p < 12; ++p) {
    short8 afr[4];
    #pragma unroll
    for (int kk = 0; kk < 4; ++kk)
      afr[kk] = *(const short8*)&h_lds[cur][l15][kk * 32 + l4 * 8];

    floatx4 acc[4];
    if (p == 0) {
      #pragma unroll
      for (int g = 0; g < 4; ++g) acc[g] = (floatx4){bias[g], bias[g], bias[g], bias[g]};
      #pragma unroll
      for (int r = 0; r < 4; ++r) {
        const int row = base_row + l4 * 4 + r;
        const floatx4 x4 = *(const floatx4*)(seq + row * 192 + 47 * 4);
        #pragma unroll
        for (int g = 0; g < 4; ++g) {
          float s = acc[g][r];
          #pragma unroll
          for (int f = 0; f < 4; ++f) s = fmaf(x4[f], wih[g][f], s);
          acc[g][r] = s;
        }
      }
    } else {
      #pragma unroll
      for (int g = 0; g < 4; ++g)
        acc[g] = (floatx4){bias_dec[g], bias_dec[g], bias_dec[g], bias_dec[g]};
    }

    #pragma unroll
    for (int g = 0; g < 4; ++g)
      #pragma unroll
      for (int kk = 0; kk < 4; ++kk)
        acc[g] = __builtin_amdgcn_mfma_f32_16x16x32_bf16(afr[kk], frag1[g][kk], acc[g], 0, 0, 0);

    #pragma unroll
    for (int r = 0; r < 4; ++r) {
      const float ig = sigm(acc[0][r]);
      const float fg = sigm(acc[1][r]);
      const float gg = tanh_(acc[2][r]);
      const float og = sigm(acc[3][r]);
      const float c  = fg * c_st[r] + ig * gg;
      c_st[r] = c;
      const float h = og * tanh_(c);
      h_lds[cur ^ 1][l4 * 4 + r][w * 16 + l15] = f2bf(h);
    }
    __syncthreads();   // h_p visible in buffer cur^1

    // out_p = h_p @ W_out^T + b_out, computed by wave (p&7). Safe without a
    // trailing barrier: the buffer written at step p is next overwritten at
    // step p+2, whose writes are gated behind barrier p+1, which this wave
    // joins only after finishing its reads.
    if (w == (p & 7)) {
      short8 ofr[4];
      #pragma unroll
      for (int kk = 0; kk < 4; ++kk)
        ofr[kk] = *(const short8*)&h_lds[cur ^ 1][l15][kk * 32 + l4 * 8];
      floatx4 acco = (floatx4){bo, bo, bo, bo};
      #pragma unroll
      for (int kk = 0; kk < 4; ++kk)
        acco = __builtin_amdgcn_mfma_f32_16x16x32_bf16(ofr[kk], wout[kk], acco, 0, 0, 0);
      if (l15 < 4) {
        #pragma unroll
        for (int r = 0; r < 4; ++r)
          out[(base_row + l4 * 4 + r) * 48 + p * 4 + l15] = acco[r];  // [B,V,P,F]
      }
    }

    // After p=0: fold W_ih @ W_out into frag1 (lane-private regs; wout_f32 is
    // read-only after init -> no extra sync needed).
    if (p == 0) {
      #pragma unroll
      for (int g = 0; g < 4; ++g)
        #pragma unroll
        for (int kk = 0; kk < 4; ++kk) {
          short8 fr = frag1[g][kk];
          #pragma unroll
          for (int i = 0; i < 8; ++i) {
            const int k = kk * 32 + l4 * 8 + i;
            float v = bf2f(fr[i]);
            #pragma unroll
            for (int f = 0; f < 4; ++f) v = fmaf(wih[g][f], wout_f32[f][k], v);
            fr[i] = f2bf(v);
          }
          frag1[g][kk] = fr;
        }
    }

    cur ^= 1;
  }
}

extern "C" void kernel_launch(void* const* d_in, const int* in_sizes, int n_in,
                              void* d_out, int out_size, void* d_ws, size_t ws_size,
                              hipStream_t stream) {
  const float* seq   = (const float*)d_in[0];
  // d_in[1..5] (dist/bearing/heading matrices, masks) unused by the reference fwd
  const float* W_ih  = (const float*)d_in[6];
  const float* W_hh  = (const float*)d_in[7];
  const float* b_ih  = (const float*)d_in[8];
  const float* b_hh  = (const float*)d_in[9];
  const float* W_out = (const float*)d_in[10];
  const float* b_out = (const float*)d_in[11];
  lstm_fused<<<512, 512, 0, stream>>>(seq, W_ih, W_hh, b_ih, b_hh, W_out, b_out,
                                      (float*)d_out);
}

// Round 10
// 239.199 us; speedup vs baseline: 1.1520x; 1.0808x over previous
//
#include <hip/hip_runtime.h>

// vanilla_lstm R10 = R9 minus register pressure: zero-spill is the goal.
// R9 evidence: 128-VGPR cap honored but live set ~130 -> spill (WRITE 26MB) ->
// per-wave scratch -> CP refuses 2nd block/CU -> occupancy stuck 23%.
// Trims vs R9 (numerics unchanged, wih stays f32):
//   - wih[4][4] (16 regs) -> LDS wih_lds[512][4], re-read 4x ds_read_b128/step
//     (same-addr broadcast across l4; 2-way alias across l15 = free).
//   - bias_dec -> computed after encode (decode-only).
// Peak live ~116 < 128 -> no spill -> 2 blocks/CU = 4 waves/SIMD.
// Geometry: 512 blocks x 16 rows, 512 threads (8 waves), __launch_bounds__(512,2).
// W_hh in VGPRs (64 regs bf16 B-frags); c-state in regs; h double-buffered in LDS.
// Decode p>=1: fused W_dec = W_hh + W_ih@W_out folded into frag1 after p=0.

typedef __attribute__((ext_vector_type(8))) short short8;   // 8 x bf16 bits
typedef __attribute__((ext_vector_type(4))) float floatx4;

static __device__ __forceinline__ short f2bf(float x) {
  union { float f; unsigned u; } v; v.f = x;
  unsigned r = (v.u + 0x7FFFu + ((v.u >> 16) & 1u)) >> 16;  // RNE
  return (short)r;
}
static __device__ __forceinline__ float bf2f(short b) {
  union { unsigned u; float f; } v; v.u = ((unsigned)(unsigned short)b) << 16;
  return v.f;
}
static __device__ __forceinline__ float sigm(float x) {
  return __builtin_amdgcn_rcpf(1.0f + __expf(-x));
}
static __device__ __forceinline__ float tanh_(float x) {
  return 1.0f - 2.0f * __builtin_amdgcn_rcpf(1.0f + __expf(2.0f * x));
}

__global__ __launch_bounds__(512, 2) void lstm_fused(
    const float* __restrict__ seq,
    const float* __restrict__ W_ih, const float* __restrict__ W_hh,
    const float* __restrict__ b_ih, const float* __restrict__ b_hh,
    const float* __restrict__ W_out, const float* __restrict__ b_out,
    float* __restrict__ out)
{
  __shared__ __align__(16) short h_lds[2][16][136];  // bf16 bits, stride 136 (pad)
  __shared__ __align__(16) float wout_f32[4][128];   // W_out staged f32
  __shared__ __align__(16) float wih_lds[512][4];    // W_ih staged f32 (reg trim)

  const int tid = threadIdx.x;
  const int w   = tid >> 6;      // wave 0..7 -> gate-col group 16w..16w+15
  const int L   = tid & 63;
  const int l15 = L & 15;
  const int l4  = L >> 4;        // 0..3
  const int base_row = blockIdx.x << 4;

  short8 frag1[4][4];   // W_hh B-frags [gate g][k-chunk kk]; col = 128g+16w+l15
  float  bias[4];       // b_ih+b_hh at lane's col
  float  c_st[4];       // cell state rows 4*l4+r, j = 16w+l15

  // ---- init: zero h buffer 0; stage W_out and W_ih into LDS ----
  {
    short* hp = &h_lds[0][0][0];
    for (int i = tid; i < 16 * 136; i += 512) hp[i] = 0;
    wout_f32[tid >> 7][tid & 127] = W_out[tid];                    // [4][128]
    *(floatx4*)&wih_lds[tid][0] = *(const floatx4*)(W_ih + tid * 4); // [512][4]
  }

  #pragma unroll
  for (int g = 0; g < 4; ++g) {
    const int col = g * 128 + w * 16 + l15;
    bias[g] = b_ih[col] + b_hh[col];
    #pragma unroll
    for (int kk = 0; kk < 4; ++kk) {
      const float* src = W_hh + col * 128 + kk * 32 + l4 * 8;
      short8 fr;
      #pragma unroll
      for (int i = 0; i < 8; ++i) fr[i] = f2bf(src[i]);
      frag1[g][kk] = fr;
    }
  }
  #pragma unroll
  for (int r = 0; r < 4; ++r) c_st[r] = 0.0f;

  __syncthreads();

  int cur = 0;

  // ===================== encode: t = 0..47 =====================
  for (int t = 0; t < 48; ++t) {
    short8 afr[4];
    #pragma unroll
    for (int kk = 0; kk < 4; ++kk)
      afr[kk] = *(const short8*)&h_lds[cur][l15][kk * 32 + l4 * 8];

    floatx4 acc[4];
    #pragma unroll
    for (int g = 0; g < 4; ++g) acc[g] = (floatx4){bias[g], bias[g], bias[g], bias[g]};

    // x-projection in fp32 (K=4); wih re-read from LDS each step (reg trim)
    {
      floatx4 wv[4];
      #pragma unroll
      for (int g = 0; g < 4; ++g)
        wv[g] = *(const floatx4*)&wih_lds[g * 128 + w * 16 + l15][0];
      #pragma unroll
      for (int r = 0; r < 4; ++r) {
        const int row = base_row + l4 * 4 + r;
        const floatx4 x4 = *(const floatx4*)(seq + row * 192 + t * 4);
        #pragma unroll
        for (int g = 0; g < 4; ++g) {
          float s = acc[g][r];
          #pragma unroll
          for (int f = 0; f < 4; ++f) s = fmaf(x4[f], wv[g][f], s);
          acc[g][r] = s;
        }
      }
    }

    #pragma unroll
    for (int g = 0; g < 4; ++g)
      #pragma unroll
      for (int kk = 0; kk < 4; ++kk)
        acc[g] = __builtin_amdgcn_mfma_f32_16x16x32_bf16(afr[kk], frag1[g][kk], acc[g], 0, 0, 0);

    #pragma unroll
    for (int r = 0; r < 4; ++r) {
      const float ig = sigm(acc[0][r]);
      const float fg = sigm(acc[1][r]);
      const float gg = tanh_(acc[2][r]);
      const float og = sigm(acc[3][r]);
      const float c  = fg * c_st[r] + ig * gg;
      c_st[r] = c;
      const float h = og * tanh_(c);
      h_lds[cur ^ 1][l4 * 4 + r][w * 16 + l15] = f2bf(h);
    }
    __syncthreads();
    cur ^= 1;
  }

  // ---- decode-only constants (kept out of the encode live-range) ----
  short8 wout[4];
  #pragma unroll
  for (int kk = 0; kk < 4; ++kk) {
    short8 fr;
    #pragma unroll
    for (int i = 0; i < 8; ++i)
      fr[i] = (l15 < 4) ? f2bf(wout_f32[l15 & 3][kk * 32 + l4 * 8 + i]) : (short)0;
    wout[kk] = fr;
  }
  const float bo = (l15 < 4) ? b_out[l15] : 0.0f;
  float bias_dec[4];
  #pragma unroll
  for (int g = 0; g < 4; ++g) {
    const int col = g * 128 + w * 16 + l15;
    float bd = bias[g];
    #pragma unroll
    for (int f = 0; f < 4; ++f) bd = fmaf(b_out[f], wih_lds[col][f], bd);
    bias_dec[g] = bd;
  }

  // ===================== decode: p = 0..11 =====================
  // p = 0: original W + f32 x-proj of seq[..,47,:]; p >= 1: fused W_dec, no x term.
  for (int p = 0; p < 12; ++p) {
    short8 afr[4];
    #pragma unroll
    for (int kk = 0; kk < 4; ++kk)
      afr[kk] = *(const short8*)&h_lds[cur][l15][kk * 32 + l4 * 8];

    floatx4 acc[4];
    if (p == 0) {
      #pragma unroll
      for (int g = 0; g < 4; ++g) acc[g] = (floatx4){bias[g], bias[g], bias[g], bias[g]};
      floatx4 wv[4];
      #pragma unroll
      for (int g = 0; g < 4; ++g)
        wv[g] = *(const floatx4*)&wih_lds[g * 128 + w * 16 + l15][0];
      #pragma unroll
      for (int r = 0; r < 4; ++r) {
        const int row = base_row + l4 * 4 + r;
        const floatx4 x4 = *(const floatx4*)(seq + row * 192 + 47 * 4);
        #pragma unroll
        for (int g = 0; g < 4; ++g) {
          float s = acc[g][r];
          #pragma unroll
          for (int f = 0; f < 4; ++f) s = fmaf(x4[f], wv[g][f], s);
          acc[g][r] = s;
        }
      }
    } else {
      #pragma unroll
      for (int g = 0; g < 4; ++g)
        acc[g] = (floatx4){bias_dec[g], bias_dec[g], bias_dec[g], bias_dec[g]};
    }

    #pragma unroll
    for (int g = 0; g < 4; ++g)
      #pragma unroll
      for (int kk = 0; kk < 4; ++kk)
        acc[g] = __builtin_amdgcn_mfma_f32_16x16x32_bf16(afr[kk], frag1[g][kk], acc[g], 0, 0, 0);

    #pragma unroll
    for (int r = 0; r < 4; ++r) {
      const float ig = sigm(acc[0][r]);
      const float fg = sigm(acc[1][r]);
      const float gg = tanh_(acc[2][r]);
      const float og = sigm(acc[3][r]);
      const float c  = fg * c_st[r] + ig * gg;
      c_st[r] = c;
      const float h = og * tanh_(c);
      h_lds[cur ^ 1][l4 * 4 + r][w * 16 + l15] = f2bf(h);
    }
    __syncthreads();   // h_p visible in buffer cur^1

    // out_p = h_p @ W_out^T + b_out, computed by wave (p&7). Safe without a
    // trailing barrier: the buffer written at step p is next overwritten at
    // step p+2, whose writes are gated behind barrier p+1, which this wave
    // joins only after finishing its reads.
    if (w == (p & 7)) {
      short8 ofr[4];
      #pragma unroll
      for (int kk = 0; kk < 4; ++kk)
        ofr[kk] = *(const short8*)&h_lds[cur ^ 1][l15][kk * 32 + l4 * 8];
      floatx4 acco = (floatx4){bo, bo, bo, bo};
      #pragma unroll
      for (int kk = 0; kk < 4; ++kk)
        acco = __builtin_amdgcn_mfma_f32_16x16x32_bf16(ofr[kk], wout[kk], acco, 0, 0, 0);
      if (l15 < 4) {
        #pragma unroll
        for (int r = 0; r < 4; ++r)
          out[(base_row + l4 * 4 + r) * 48 + p * 4 + l15] = acco[r];  // [B,V,P,F]
      }
    }

    // After p=0: fold W_ih @ W_out into frag1 (lane-private regs; wih_lds and
    // wout_f32 are read-only after init -> no extra sync needed).
    if (p == 0) {
      #pragma unroll
      for (int g = 0; g < 4; ++g) {
        const int col = g * 128 + w * 16 + l15;
        const floatx4 wv = *(const floatx4*)&wih_lds[col][0];
        #pragma unroll
        for (int kk = 0; kk < 4; ++kk) {
          short8 fr = frag1[g][kk];
          #pragma unroll
          for (int i = 0; i < 8; ++i) {
            const int k = kk * 32 + l4 * 8 + i;
            float v = bf2f(fr[i]);
            #pragma unroll
            for (int f = 0; f < 4; ++f) v = fmaf(wv[f], wout_f32[f][k], v);
            fr[i] = f2bf(v);
          }
          frag1[g][kk] = fr;
        }
      }
    }

    cur ^= 1;
  }
}

extern "C" void kernel_launch(void* const* d_in, const int* in_sizes, int n_in,
                              void* d_out, int out_size, void* d_ws, size_t ws_size,
                              hipStream_t stream) {
  const float* seq   = (const float*)d_in[0];
  // d_in[1..5] (dist/bearing/heading matrices, masks) unused by the reference fwd
  const float* W_ih  = (const float*)d_in[6];
  const float* W_hh  = (const float*)d_in[7];
  const float* b_ih  = (const float*)d_in[8];
  const float* b_hh  = (const float*)d_in[9];
  const float* W_out = (const float*)d_in[10];
  const float* b_out = (const float*)d_in[11];
  lstm_fused<<<512, 512, 0, stream>>>(seq, W_ih, W_hh, b_ih, b_hh, W_out, b_out,
                                      (float*)d_out);
}